// Round 1
// baseline (20440.880 us; speedup 1.0000x reference)
//
#include <hip/hip_runtime.h>
#include <stdint.h>

#define BATCH 32768
#define TT    25
#define IND   16
#define HD    64

__device__ __forceinline__ float sigm(float x){ return 1.0f/(1.0f + __expf(-x)); }
__device__ __forceinline__ float tanh_fast(float x){
  float ax = fabsf(x);
  float t  = __expf(-2.0f*ax);
  float r  = (1.0f - t)/(1.0f + t);
  return copysignf(r, x);
}
// RNE float->bf16 (returns low 16 bits)
__device__ __forceinline__ uint32_t f2bf(float v){
  uint32_t u = __float_as_uint(v);
  return (u + 0x7fffu + ((u >> 16) & 1u)) >> 16;
}

// ---------------- Kernel 1: both LSTM layers, lockstep over t ----------------
// sample-per-lane: 64 threads/block = 64 samples. Weights via lane-uniform
// scalar loads. h0/h1 in registers (static k indexing); c0/c1/h-new in per-lane
// LDS columns ([u][lane] => 2 lanes/bank, conflict-free) to allow dynamic u.
__global__ __launch_bounds__(64, 1) void lstm2_kernel(
    const float* __restrict__ x,
    const float* __restrict__ wih0, const float* __restrict__ whh0,
    const float* __restrict__ bih0, const float* __restrict__ bhh0,
    const float* __restrict__ wih1, const float* __restrict__ whh1,
    const float* __restrict__ bih1, const float* __restrict__ bhh1,
    uint32_t* __restrict__ flat)            // [BATCH][TT*HD/2] packed bf16 pairs
{
  __shared__ float cs0[HD][64];
  __shared__ float cs1[HD][64];
  __shared__ float hnw[HD][64];

  const int lane = threadIdx.x;
  const int s    = blockIdx.x * 64 + lane;

  float h0[HD], h1[HD];
  #pragma unroll
  for (int u = 0; u < HD; u++){
    h0[u] = 0.f; h1[u] = 0.f;
    cs0[u][lane] = 0.f; cs1[u][lane] = 0.f;
  }

  const float* xs   = x + (size_t)s * TT * IND;
  uint32_t*    frow = flat + (size_t)s * (TT * HD / 2);

  #pragma unroll 1
  for (int t = 0; t < TT; t++){
    float xv[IND];
    #pragma unroll
    for (int i = 0; i < IND/4; i++){
      const float4 v = ((const float4*)xs)[t*(IND/4) + i];
      xv[4*i+0]=v.x; xv[4*i+1]=v.y; xv[4*i+2]=v.z; xv[4*i+3]=v.w;
    }

    // ---- layer 0: gates = b + W_ih x_t + W_hh h0 ----
    #pragma unroll 1
    for (int u = 0; u < HD; u++){
      float ai = bih0[u]      + bhh0[u];
      float af = bih0[HD+u]   + bhh0[HD+u];
      float ag = bih0[2*HD+u] + bhh0[2*HD+u];
      float ao = bih0[3*HD+u] + bhh0[3*HD+u];
      const float* wi = wih0 + u*IND;
      #pragma unroll
      for (int k = 0; k < IND; k++){
        ai += xv[k]*wi[k];
        af += xv[k]*wi[HD*IND + k];
        ag += xv[k]*wi[2*HD*IND + k];
        ao += xv[k]*wi[3*HD*IND + k];
      }
      const float* wh = whh0 + u*HD;
      #pragma unroll
      for (int k = 0; k < HD; k++){
        ai += h0[k]*wh[k];
        af += h0[k]*wh[HD*HD + k];
        ag += h0[k]*wh[2*HD*HD + k];
        ao += h0[k]*wh[3*HD*HD + k];
      }
      float ig = sigm(ai), fg = sigm(af), gg = tanh_fast(ag), og = sigm(ao);
      float c  = fg*cs0[u][lane] + ig*gg;
      cs0[u][lane] = c;
      hnw[u][lane] = og * tanh_fast(c);
    }
    #pragma unroll
    for (int u = 0; u < HD; u++) h0[u] = hnw[u][lane];

    // ---- layer 1: gates = b + W_ih h0 + W_hh h1 ----
    #pragma unroll 1
    for (int u = 0; u < HD; u++){
      float ai = bih1[u]      + bhh1[u];
      float af = bih1[HD+u]   + bhh1[HD+u];
      float ag = bih1[2*HD+u] + bhh1[2*HD+u];
      float ao = bih1[3*HD+u] + bhh1[3*HD+u];
      const float* wi = wih1 + u*HD;
      const float* wh = whh1 + u*HD;
      #pragma unroll
      for (int k = 0; k < HD; k++){
        ai += h0[k]*wi[k]           + h1[k]*wh[k];
        af += h0[k]*wi[HD*HD + k]   + h1[k]*wh[HD*HD + k];
        ag += h0[k]*wi[2*HD*HD + k] + h1[k]*wh[2*HD*HD + k];
        ao += h0[k]*wi[3*HD*HD + k] + h1[k]*wh[3*HD*HD + k];
      }
      float ig = sigm(ai), fg = sigm(af), gg = tanh_fast(ag), og = sigm(ao);
      float c  = fg*cs1[u][lane] + ig*gg;
      cs1[u][lane] = c;
      hnw[u][lane] = og * tanh_fast(c);
    }
    #pragma unroll
    for (int u = 0; u < HD; u++) h1[u] = hnw[u][lane];

    // ---- store h1[t] to flat as packed bf16 ----
    #pragma unroll
    for (int p = 0; p < HD/2; p++){
      uint32_t lo = f2bf(h1[2*p]);
      uint32_t hi = f2bf(h1[2*p+1]);
      frow[t*(HD/2) + p] = lo | (hi << 16);
    }
  }
}

// ---------------- Kernel 2: 3 FC heads + small linears ----------------
// thread = sample; blockIdx.y = head. acc[128] fully unrolled (static reg
// indexing). FC weights via lane-uniform scalar loads; flat via 16B bf16 packs.
__global__ __launch_bounds__(256, 2) void fc_heads_kernel(
    const uint32_t* __restrict__ flat,
    const float* __restrict__ fc1w, const float* __restrict__ fc1b,
    const float* __restrict__ fc2w, const float* __restrict__ fc2b,
    const float* __restrict__ fc3w, const float* __restrict__ fc3b,
    const float* __restrict__ l1w,  const float* __restrict__ l1b,
    const float* __restrict__ l2w,  const float* __restrict__ l2b,
    const float* __restrict__ l3w,  const float* __restrict__ l3b,
    float* __restrict__ out)
{
  const int head = blockIdx.y;
  const float* W  = head==0 ? fc1w : (head==1 ? fc2w : fc3w);
  const float* Wb = head==0 ? fc1b : (head==1 ? fc2b : fc3b);
  const float* L  = head==0 ? l1w  : (head==1 ? l2w  : l3w);
  const float* Lb = head==0 ? l1b  : (head==1 ? l2b  : l3b);
  const int odim  = head==0 ? 5 : (head==1 ? 4 : 8);
  float* op = out + (head==0 ? (size_t)0 : (head==1 ? (size_t)BATCH*5 : (size_t)BATCH*9));

  const int s = blockIdx.x * 256 + threadIdx.x;
  const uint32_t* fr = flat + (size_t)s * (TT*HD/2);

  float acc[128];
  #pragma unroll
  for (int j = 0; j < 128; j++) acc[j] = Wb[j];

  #pragma unroll 1
  for (int k0 = 0; k0 < TT*HD; k0 += 8){
    const uint4 pk = *((const uint4*)(fr + k0/2));
    float f[8];
    f[0]=__uint_as_float(pk.x<<16); f[1]=__uint_as_float(pk.x&0xffff0000u);
    f[2]=__uint_as_float(pk.y<<16); f[3]=__uint_as_float(pk.y&0xffff0000u);
    f[4]=__uint_as_float(pk.z<<16); f[5]=__uint_as_float(pk.z&0xffff0000u);
    f[6]=__uint_as_float(pk.w<<16); f[7]=__uint_as_float(pk.w&0xffff0000u);
    #pragma unroll
    for (int j = 0; j < 128; j++){
      const float* wr = W + j*(TT*HD) + k0;
      float a = acc[j];
      #pragma unroll
      for (int kk = 0; kk < 8; kk++) a += f[kk]*wr[kk];
      acc[j] = a;
    }
  }

  #pragma unroll
  for (int j = 0; j < 128; j++) acc[j] = fmaxf(acc[j], 0.f);

  #pragma unroll 1
  for (int m = 0; m < odim; m++){
    float o = Lb[m];
    #pragma unroll
    for (int j = 0; j < 128; j++) o += acc[j]*L[m*128 + j];
    op[(size_t)s*odim + m] = o;
  }
}

extern "C" void kernel_launch(void* const* d_in, const int* in_sizes, int n_in,
                              void* d_out, int out_size, void* d_ws, size_t ws_size,
                              hipStream_t stream)
{
  const float* x    = (const float*)d_in[0];
  const float* wih0 = (const float*)d_in[1];
  const float* whh0 = (const float*)d_in[2];
  const float* bih0 = (const float*)d_in[3];
  const float* bhh0 = (const float*)d_in[4];
  const float* wih1 = (const float*)d_in[5];
  const float* whh1 = (const float*)d_in[6];
  const float* bih1 = (const float*)d_in[7];
  const float* bhh1 = (const float*)d_in[8];
  const float* fc1w = (const float*)d_in[9];
  const float* fc1b = (const float*)d_in[10];
  const float* fc2w = (const float*)d_in[11];
  const float* fc2b = (const float*)d_in[12];
  const float* fc3w = (const float*)d_in[13];
  const float* fc3b = (const float*)d_in[14];
  const float* l1w  = (const float*)d_in[15];
  const float* l1b  = (const float*)d_in[16];
  const float* l2w  = (const float*)d_in[17];
  const float* l2b  = (const float*)d_in[18];
  const float* l3w  = (const float*)d_in[19];
  const float* l3b  = (const float*)d_in[20];

  float*    out  = (float*)d_out;
  uint32_t* flat = (uint32_t*)d_ws;

  const size_t need = (size_t)BATCH * TT * HD * 2;  // bf16 flat buffer
  if (ws_size < need) return;  // insufficient scratch -> visible validation fail

  lstm2_kernel<<<dim3(BATCH/64), dim3(64), 0, stream>>>(
      x, wih0, whh0, bih0, bhh0, wih1, whh1, bih1, bhh1, flat);

  fc_heads_kernel<<<dim3(BATCH/256, 3), dim3(256), 0, stream>>>(
      flat, fc1w, fc1b, fc2w, fc2b, fc3w, fc3b,
      l1w, l1b, l2w, l2b, l3w, l3b, out);
}

// Round 2
// 524.861 us; speedup vs baseline: 38.9453x; 38.9453x over previous
//
#include <hip/hip_runtime.h>
#include <stdint.h>

#define BATCH 32768
#define TT    25
#define HD    64

typedef float f32x4 __attribute__((ext_vector_type(4)));
typedef short s16x8 __attribute__((ext_vector_type(8)));

// fc1w|fc2w|fc3w concatenated, bf16, row-major [384][1600]
__device__ __align__(16) short g_Wc[384 * 1600];

__device__ __forceinline__ float sigm(float x){ return 1.0f/(1.0f + __expf(-x)); }
__device__ __forceinline__ float tanh_fast(float x){
  float ax = fabsf(x);
  float t  = __expf(-2.0f*ax);
  float r  = (1.0f - t)/(1.0f + t);
  return copysignf(r, x);
}
__device__ __forceinline__ uint32_t f2bf(float v){
  uint32_t u = __float_as_uint(v);
  return (u + 0x7fffu + ((u >> 16) & 1u)) >> 16;   // RNE
}
__device__ __forceinline__ short f2bfs(float v){ return (short)f2bf(v); }

// ---------------- prologue: convert FC weights to bf16 ----------------
__global__ void conv_wc_kernel(const float* __restrict__ fc1w,
                               const float* __restrict__ fc2w,
                               const float* __restrict__ fc3w){
  const int j = blockIdx.x;
  const float* src = (j < 128) ? fc1w + j*1600
                   : (j < 256) ? fc2w + (j-128)*1600
                               : fc3w + (j-256)*1600;
  for (int k = threadIdx.x; k < 1600; k += 256)
    g_Wc[j*1600 + k] = f2bfs(src[k]);
}

// ---------------- Kernel 1: both LSTM layers via MFMA ----------------
// Block: 64 samples, 4 waves. Wave w owns units [16w,16w+16), gates reordered
// [i,f,g,o] per 16-unit tile so acc n-tiles 0..3 = i,f,g,o of the same units.
// A LDS row (per sample, 160 k): [x(16)|pad(16)|h0(64)|h1(64)], XOR-swizzled.
__global__ __launch_bounds__(256,1) void lstm2_mfma_kernel(
    const float* __restrict__ x,
    const float* __restrict__ wih0, const float* __restrict__ whh0,
    const float* __restrict__ bih0, const float* __restrict__ bhh0,
    const float* __restrict__ wih1, const float* __restrict__ whh1,
    const float* __restrict__ bih1, const float* __restrict__ bhh1,
    short* __restrict__ flat)                 // [BATCH][1600] bf16
{
  __shared__ short Alds[64*160];    // 20 KiB
  __shared__ short W0s[256*96];     // 48 KiB  rows: [x16|zero16|h64]
  __shared__ short W1s[256*128];    // 64 KiB  rows: [h0 64|h1 64]
  char* const Ab  = (char*)Alds;
  char* const W0b = (char*)W0s;
  char* const W1b = (char*)W1s;

  const int tid  = threadIdx.x;
  const int lane = tid & 63;
  const int wv   = tid >> 6;
  const int lrow = lane & 15;
  const int lk   = lane >> 4;
  const int sw   = (lrow & 7) << 4;     // row-swizzle for all frag reads
  const int sb   = blockIdx.x * 64;
  const int u    = wv*16 + lrow;        // this lane's global unit id

  // ---- stage weights: one LDS row per thread, gate-remapped ----
  {
    const int n   = tid;                               // LDS row
    const int g   = ((n>>4)&3)*64 + (n>>6)*16 + (n&15); // global gate row
    const int nsw = (n & 7) << 4;
    const float* r0 = wih1 + g*64;
    #pragma unroll
    for (int c = 0; c < 8; c++){
      s16x8 v;
      #pragma unroll
      for (int j = 0; j < 8; j++) v[j] = f2bfs(r0[c*8+j]);
      *(s16x8*)(W1b + ((n*256 + c*16) ^ nsw)) = v;
    }
    const float* r1 = whh1 + g*64;
    #pragma unroll
    for (int c = 0; c < 8; c++){
      s16x8 v;
      #pragma unroll
      for (int j = 0; j < 8; j++) v[j] = f2bfs(r1[c*8+j]);
      *(s16x8*)(W1b + ((n*256 + 128 + c*16) ^ nsw)) = v;
    }
    const float* r2 = wih0 + g*16;
    #pragma unroll
    for (int c = 0; c < 2; c++){
      s16x8 v;
      #pragma unroll
      for (int j = 0; j < 8; j++) v[j] = f2bfs(r2[c*8+j]);
      *(s16x8*)(W0b + ((n*192 + c*16) ^ nsw)) = v;
    }
    s16x8 z = {0,0,0,0,0,0,0,0};
    *(s16x8*)(W0b + ((n*192 + 32) ^ nsw)) = z;
    *(s16x8*)(W0b + ((n*192 + 48) ^ nsw)) = z;
    const float* r3 = whh0 + g*64;
    #pragma unroll
    for (int c = 0; c < 8; c++){
      s16x8 v;
      #pragma unroll
      for (int j = 0; j < 8; j++) v[j] = f2bfs(r3[c*8+j]);
      *(s16x8*)(W0b + ((n*192 + 64 + c*16) ^ nsw)) = v;
    }
  }

  // ---- zero A pad + h regions (bytes 32..320 of each row) ----
  {
    s16x8 z = {0,0,0,0,0,0,0,0};
    #pragma unroll
    for (int it = 0; it < 5; it++){
      int idx = tid + it*256;
      if (idx < 64*18){
        int s = idx/18, c = idx - s*18;
        *(s16x8*)(Ab + ((s*320 + 32 + c*16) ^ ((s&7)<<4))) = z;
      }
    }
  }
  // ---- stage x_0 ----
  {
    int s = tid >> 2, q = tid & 3;
    float4 v = *(const float4*)(x + (size_t)(sb+s)*(TT*16) + q*4);
    uint2 p; p.x = f2bf(v.x) | (f2bf(v.y) << 16);
             p.y = f2bf(v.z) | (f2bf(v.w) << 16);
    *(uint2*)(Ab + ((s*320 + q*8) ^ ((s&7)<<4))) = p;
  }
  // ---- per-lane biases (i,f,g,o for unit u) ----
  float b0v[4], b1v[4];
  #pragma unroll
  for (int tq = 0; tq < 4; tq++){
    b0v[tq] = bih0[tq*64+u] + bhh0[tq*64+u];
    b1v[tq] = bih1[tq*64+u] + bhh1[tq*64+u];
  }
  float c0[4][4], c1[4][4];
  #pragma unroll
  for (int m = 0; m < 4; m++)
    #pragma unroll
    for (int r = 0; r < 4; r++){ c0[m][r] = 0.f; c1[m][r] = 0.f; }

  __syncthreads();

  #pragma unroll 1
  for (int t = 0; t < TT; t++){
    // ======== layer 0: K-tiles 0..2 (x|pad|h0) ========
    f32x4 acc[4][4];
    #pragma unroll
    for (int m = 0; m < 4; m++)
      #pragma unroll
      for (int n = 0; n < 4; n++){ f32x4 iv = {b0v[n],b0v[n],b0v[n],b0v[n]}; acc[m][n] = iv; }
    #pragma unroll
    for (int kt = 0; kt < 3; kt++){
      s16x8 a[4], b[4];
      #pragma unroll
      for (int m = 0; m < 4; m++)
        a[m] = *(const s16x8*)(Ab + (((m*16+lrow)*320 + kt*64 + lk*16) ^ sw));
      #pragma unroll
      for (int n = 0; n < 4; n++)
        b[n] = *(const s16x8*)(W0b + (((wv*64+n*16+lrow)*192 + kt*64 + lk*16) ^ sw));
      #pragma unroll
      for (int m = 0; m < 4; m++)
        #pragma unroll
        for (int n = 0; n < 4; n++)
          acc[m][n] = __builtin_amdgcn_mfma_f32_16x16x32_bf16(a[m], b[n], acc[m][n], 0, 0, 0);
    }
    short hb[4][4];
    #pragma unroll
    for (int m = 0; m < 4; m++)
      #pragma unroll
      for (int r = 0; r < 4; r++){
        float iv = sigm(acc[m][0][r]);
        float fv = sigm(acc[m][1][r]);
        float gv = tanh_fast(acc[m][2][r]);
        float ov = sigm(acc[m][3][r]);
        float c  = fv*c0[m][r] + iv*gv; c0[m][r] = c;
        hb[m][r] = f2bfs(ov * tanh_fast(c));
      }
    __syncthreads();                       // all waves done reading h0_{t-1}, x_t
    #pragma unroll
    for (int m = 0; m < 4; m++)
      #pragma unroll
      for (int r = 0; r < 4; r++){
        int s = m*16 + lk*4 + r;
        *(short*)(Ab + ((s*320 + 64 + u*2) ^ ((s&7)<<4))) = hb[m][r];
      }
    if (t + 1 < TT){
      int s = tid >> 2, q = tid & 3;
      float4 v = *(const float4*)(x + (size_t)(sb+s)*(TT*16) + (t+1)*16 + q*4);
      uint2 p; p.x = f2bf(v.x) | (f2bf(v.y) << 16);
               p.y = f2bf(v.z) | (f2bf(v.w) << 16);
      *(uint2*)(Ab + ((s*320 + q*8) ^ ((s&7)<<4))) = p;
    }
    __syncthreads();                       // h0_t visible
    // ======== layer 1: K-tiles over A k=32..159 (h0_t|h1_{t-1}) ========
    #pragma unroll
    for (int m = 0; m < 4; m++)
      #pragma unroll
      for (int n = 0; n < 4; n++){ f32x4 iv = {b1v[n],b1v[n],b1v[n],b1v[n]}; acc[m][n] = iv; }
    #pragma unroll
    for (int kt = 0; kt < 4; kt++){
      s16x8 a[4], b[4];
      #pragma unroll
      for (int m = 0; m < 4; m++)
        a[m] = *(const s16x8*)(Ab + (((m*16+lrow)*320 + 64 + kt*64 + lk*16) ^ sw));
      #pragma unroll
      for (int n = 0; n < 4; n++)
        b[n] = *(const s16x8*)(W1b + (((wv*64+n*16+lrow)*256 + kt*64 + lk*16) ^ sw));
      #pragma unroll
      for (int m = 0; m < 4; m++)
        #pragma unroll
        for (int n = 0; n < 4; n++)
          acc[m][n] = __builtin_amdgcn_mfma_f32_16x16x32_bf16(a[m], b[n], acc[m][n], 0, 0, 0);
    }
    #pragma unroll
    for (int m = 0; m < 4; m++)
      #pragma unroll
      for (int r = 0; r < 4; r++){
        float iv = sigm(acc[m][0][r]);
        float fv = sigm(acc[m][1][r]);
        float gv = tanh_fast(acc[m][2][r]);
        float ov = sigm(acc[m][3][r]);
        float c  = fv*c1[m][r] + iv*gv; c1[m][r] = c;
        hb[m][r] = f2bfs(ov * tanh_fast(c));
      }
    __syncthreads();                       // all waves done reading h1_{t-1}
    #pragma unroll
    for (int m = 0; m < 4; m++)
      #pragma unroll
      for (int r = 0; r < 4; r++){
        int s = m*16 + lk*4 + r;
        *(short*)(Ab + ((s*320 + 192 + u*2) ^ ((s&7)<<4))) = hb[m][r];
        flat[(size_t)(sb+s)*1600 + t*64 + u] = hb[m][r];
      }
    __syncthreads();                       // h1_t visible
  }
}

// ---------------- Kernel 2: FC GEMM (M=32768,N=384,K=1600) + heads ----------------
__global__ __launch_bounds__(256,2) void fc_mfma_kernel(
    const short* __restrict__ flat,
    const float* __restrict__ fc1b, const float* __restrict__ fc2b, const float* __restrict__ fc3b,
    const float* __restrict__ l1w,  const float* __restrict__ l1b,
    const float* __restrict__ l2w,  const float* __restrict__ l2b,
    const float* __restrict__ l3w,  const float* __restrict__ l3b,
    float* __restrict__ out)
{
  __shared__ float R[64*388];     // relu'd [64 samples][384 fc], padded
  const int tid  = threadIdx.x;
  const int lane = tid & 63;
  const int wv   = tid >> 6;      // wave owns fc cols [96w, 96w+96)
  const int lrow = lane & 15;
  const int lk   = lane >> 4;
  const int sb   = blockIdx.x * 64;

  f32x4 acc[4][6];
  #pragma unroll
  for (int n = 0; n < 6; n++){
    int j = wv*96 + n*16 + lrow;
    float bv = (j < 128) ? fc1b[j] : (j < 256) ? fc2b[j-128] : fc3b[j-256];
    #pragma unroll
    for (int m = 0; m < 4; m++){ f32x4 iv = {bv,bv,bv,bv}; acc[m][n] = iv; }
  }

  const char* Abase = (const char*)(flat + (size_t)sb*1600);
  const char* Bbase = (const char*)g_Wc;
  #pragma unroll 1
  for (int kc = 0; kc < 50; kc++){
    s16x8 a[4], b[6];
    #pragma unroll
    for (int m = 0; m < 4; m++)
      a[m] = *(const s16x8*)(Abase + (size_t)(m*16+lrow)*3200 + kc*64 + lk*16);
    #pragma unroll
    for (int n = 0; n < 6; n++)
      b[n] = *(const s16x8*)(Bbase + (size_t)(wv*96+n*16+lrow)*3200 + kc*64 + lk*16);
    #pragma unroll
    for (int m = 0; m < 4; m++)
      #pragma unroll
      for (int n = 0; n < 6; n++)
        acc[m][n] = __builtin_amdgcn_mfma_f32_16x16x32_bf16(a[m], b[n], acc[m][n], 0, 0, 0);
  }

  #pragma unroll
  for (int m = 0; m < 4; m++)
    #pragma unroll
    for (int n = 0; n < 6; n++)
      #pragma unroll
      for (int r = 0; r < 4; r++){
        int s  = m*16 + lk*4 + r;
        int fc = wv*96 + n*16 + lrow;
        R[s*388 + fc] = fmaxf(acc[m][n][r], 0.f);
      }
  __syncthreads();

  const int s   = tid & 63;
  const int grp = tid >> 6;
  const float* Rrow = &R[s*388];
  if (grp == 0){
    #pragma unroll
    for (int mi = 0; mi < 5; mi++){
      float o = l1b[mi];
      const float* wp = l1w + mi*128;
      #pragma unroll
      for (int k = 0; k < 128; k += 4){
        float4 rv = *(const float4*)(Rrow + k);
        o += rv.x*wp[k] + rv.y*wp[k+1] + rv.z*wp[k+2] + rv.w*wp[k+3];
      }
      out[(size_t)(sb+s)*5 + mi] = o;
    }
  } else if (grp == 1){
    #pragma unroll
    for (int mi = 0; mi < 4; mi++){
      float o = l2b[mi];
      const float* wp = l2w + mi*128;
      #pragma unroll
      for (int k = 0; k < 128; k += 4){
        float4 rv = *(const float4*)(Rrow + 128 + k);
        o += rv.x*wp[k] + rv.y*wp[k+1] + rv.z*wp[k+2] + rv.w*wp[k+3];
      }
      out[(size_t)BATCH*5 + (size_t)(sb+s)*4 + mi] = o;
    }
  } else {
    const int mo = (grp == 3) ? 4 : 0;
    #pragma unroll
    for (int mi = 0; mi < 4; mi++){
      float o = l3b[mo+mi];
      const float* wp = l3w + (mo+mi)*128;
      #pragma unroll
      for (int k = 0; k < 128; k += 4){
        float4 rv = *(const float4*)(Rrow + 256 + k);
        o += rv.x*wp[k] + rv.y*wp[k+1] + rv.z*wp[k+2] + rv.w*wp[k+3];
      }
      out[(size_t)BATCH*9 + (size_t)(sb+s)*8 + mo + mi] = o;
    }
  }
}

extern "C" void kernel_launch(void* const* d_in, const int* in_sizes, int n_in,
                              void* d_out, int out_size, void* d_ws, size_t ws_size,
                              hipStream_t stream)
{
  const float* x    = (const float*)d_in[0];
  const float* wih0 = (const float*)d_in[1];
  const float* whh0 = (const float*)d_in[2];
  const float* bih0 = (const float*)d_in[3];
  const float* bhh0 = (const float*)d_in[4];
  const float* wih1 = (const float*)d_in[5];
  const float* whh1 = (const float*)d_in[6];
  const float* bih1 = (const float*)d_in[7];
  const float* bhh1 = (const float*)d_in[8];
  const float* fc1w = (const float*)d_in[9];
  const float* fc1b = (const float*)d_in[10];
  const float* fc2w = (const float*)d_in[11];
  const float* fc2b = (const float*)d_in[12];
  const float* fc3w = (const float*)d_in[13];
  const float* fc3b = (const float*)d_in[14];
  const float* l1w  = (const float*)d_in[15];
  const float* l1b  = (const float*)d_in[16];
  const float* l2w  = (const float*)d_in[17];
  const float* l2b  = (const float*)d_in[18];
  const float* l3w  = (const float*)d_in[19];
  const float* l3b  = (const float*)d_in[20];

  float* out  = (float*)d_out;
  short* flat = (short*)d_ws;
  if (ws_size < (size_t)BATCH*1600*2) return;

  conv_wc_kernel<<<dim3(384), dim3(256), 0, stream>>>(fc1w, fc2w, fc3w);

  lstm2_mfma_kernel<<<dim3(BATCH/64), dim3(256), 0, stream>>>(
      x, wih0, whh0, bih0, bhh0, wih1, whh1, bih1, bhh1, flat);

  fc_mfma_kernel<<<dim3(BATCH/64), dim3(256), 0, stream>>>(
      flat, fc1b, fc2b, fc3b, l1w, l1b, l2w, l2b, l3w, l3b, out);
}